// Round 5
// baseline (399.453 us; speedup 1.0000x reference)
//
#include <hip/hip_runtime.h>

// GCN 2-layer on MI355X — Round 15: LDS-atomic histogram aggregation.
// R11/R13/R14 all plateaued at 47-50us because every design kept a
// serialized per-node reduction (lane-run walk / shfl-scan / scalar LDS
// sum loop). New: partition accumulator lives in LDS (2048 nodes, SoA
// planes so ds_add_f32 banks are random ~2-way, not 8-way); blocks stride
// UNSORTED partition edges (perfect balance, no inner barriers):
//   coalesced packed read -> random L2 gather -> ds_add_f32 x comps.
// Sub-blocks dump partials (coalesced); combine kernels sum SB partials
// and run the fused epilogue. localC (counting sort, 86KB LDS, 1 blk/CU)
// is DELETED — degrees come from a cheap LDS int-hist pass.
//
// g[j] = x[j]*dinv[j].  layer1: hs2 via relu(dinv*(sum g)+b1)@W2*dinv
// layer2: out[i] = dinv[i]*(sum hs2[src]+hs2[i]) + b2
//
// ws: colTotal|colStart|cntmatA[B1*P]|packed[E]|dinv|g|hs2|partial-region
//     (deg/part1/part2 time-overlaid in one 4.9M-word region)  ~51 MB

#define EPB   8192   // edges per pass-A block
#define PART  2048   // nodes per partition
#define LPBIT 11
#define SRCB  18     // src bits in packed
#define SBD   6      // deghist sub-blocks per partition
#define SB1   12     // agg1 sub-blocks per partition
#define SB2   6      // agg2 sub-blocks per partition

// ---------------- Pass A ----------------

__global__ __launch_bounds__(512) void countA_kernel(
    const int* __restrict__ dst, int* __restrict__ cntmat, int E, int P) {
    __shared__ int cnt[128];
    int tid = threadIdx.x;
    if (tid < 128) cnt[tid] = 0;
    __syncthreads();
    int nv4 = E >> 2;
    int b4 = (blockIdx.x * EPB) >> 2;
    int e4 = min(b4 + (EPB >> 2), nv4);
    const int4* d4 = (const int4*)dst;
    #pragma unroll
    for (int k = 0; k < (EPB >> 2); k += 512) {
        int i = b4 + k + tid;
        if (i < e4) {
            int4 d = d4[i];
            atomicAdd(&cnt[d.x >> LPBIT], 1);
            atomicAdd(&cnt[d.y >> LPBIT], 1);
            atomicAdd(&cnt[d.z >> LPBIT], 1);
            atomicAdd(&cnt[d.w >> LPBIT], 1);
        }
    }
    if (blockIdx.x == gridDim.x - 1) {  // scalar tail (E % 4)
        int e = (nv4 << 2) + tid;
        if (e < E) atomicAdd(&cnt[dst[e] >> LPBIT], 1);
    }
    __syncthreads();
    int* row = cntmat + (size_t)blockIdx.x * P;
    if (tid < P) row[tid] = cnt[tid];
}

__global__ __launch_bounds__(256) void colscanA_kernel(
    int* __restrict__ cntmat, int* __restrict__ colTotal, int B, int P) {
    __shared__ int sdata[256];
    int p = blockIdx.x, tid = threadIdx.x;
    int v[4];
    int s = 0;
    #pragma unroll
    for (int k = 0; k < 4; k++) {
        int b = tid * 4 + k;
        v[k] = (b < B) ? cntmat[(size_t)b * P + p] : 0;
        s += v[k];
    }
    int x = s;
    sdata[tid] = x;
    __syncthreads();
    for (int off = 1; off < 256; off <<= 1) {
        int t = (tid >= off) ? sdata[tid - off] : 0;
        __syncthreads();
        x += t;
        sdata[tid] = x;
        __syncthreads();
    }
    int run = x - s;
    #pragma unroll
    for (int k = 0; k < 4; k++) {
        int b = tid * 4 + k;
        if (b < B) cntmat[(size_t)b * P + p] = run;
        run += v[k];
    }
    if (tid == 255) colTotal[p] = x;
}

__global__ __launch_bounds__(256) void totalscanA_kernel(
    const int* __restrict__ colTotal, int* __restrict__ colStart,
    int P, int E) {
    __shared__ int sdata[256];
    int tid = threadIdx.x;
    int v[4];
    int s = 0;
    #pragma unroll
    for (int k = 0; k < 4; k++) {
        int i = tid * 4 + k;
        v[k] = (i < P) ? colTotal[i] : 0;
        s += v[k];
    }
    int x = s;
    sdata[tid] = x;
    __syncthreads();
    for (int off = 1; off < 256; off <<= 1) {
        int t = (tid >= off) ? sdata[tid - off] : 0;
        __syncthreads();
        x += t;
        sdata[tid] = x;
        __syncthreads();
    }
    int run = x - s;
    #pragma unroll
    for (int k = 0; k < 4; k++) {
        int i = tid * 4 + k;
        if (i < P) colStart[i] = run;
        run += v[k];
    }
    if (tid == 0) colStart[P] = E;
}

__global__ __launch_bounds__(512) void scatterA_kernel(
    const int* __restrict__ src, const int* __restrict__ dst,
    const int* __restrict__ cntmat, const int* __restrict__ colStart,
    unsigned* __restrict__ packed, int E, int P) {
    __shared__ int cur[128];
    int tid = threadIdx.x;
    if (tid < P) cur[tid] = colStart[tid] + cntmat[(size_t)blockIdx.x * P + tid];
    __syncthreads();
    int nv4 = E >> 2;
    int b4 = (blockIdx.x * EPB) >> 2;
    int e4 = min(b4 + (EPB >> 2), nv4);
    const int4* d4 = (const int4*)dst;
    const int4* s4 = (const int4*)src;
    #pragma unroll
    for (int k = 0; k < (EPB >> 2); k += 512) {
        int i = b4 + k + tid;
        if (i < e4) {
            int4 d = d4[i];
            int4 sv = s4[i];
            int p0 = atomicAdd(&cur[d.x >> LPBIT], 1);
            packed[p0] = ((unsigned)(d.x & (PART - 1)) << SRCB) | (unsigned)sv.x;
            int p1 = atomicAdd(&cur[d.y >> LPBIT], 1);
            packed[p1] = ((unsigned)(d.y & (PART - 1)) << SRCB) | (unsigned)sv.y;
            int p2 = atomicAdd(&cur[d.z >> LPBIT], 1);
            packed[p2] = ((unsigned)(d.z & (PART - 1)) << SRCB) | (unsigned)sv.z;
            int p3 = atomicAdd(&cur[d.w >> LPBIT], 1);
            packed[p3] = ((unsigned)(d.w & (PART - 1)) << SRCB) | (unsigned)sv.w;
        }
    }
    if (blockIdx.x == gridDim.x - 1) {  // scalar tail
        int e = (nv4 << 2) + tid;
        if (e < E) {
            int d = dst[e];
            int pos = atomicAdd(&cur[d >> LPBIT], 1);
            packed[pos] = ((unsigned)(d & (PART - 1)) << SRCB) | (unsigned)src[e];
        }
    }
}

// ---------------- deghist: LDS int histogram of local dst ----------------

__global__ __launch_bounds__(512) void deghist_kernel(
    const unsigned* __restrict__ packed, const int* __restrict__ colStart,
    int* __restrict__ degpart) {
    __shared__ int cnt[PART];
    int tid = threadIdx.x;
    int p = blockIdx.x / SBD, sb = blockIdx.x - p * SBD;
    int s0 = colStart[p], len = colStart[p + 1] - s0;
    int lo = s0 + (int)(((long long)len * sb) / SBD);
    int hi = s0 + (int)(((long long)len * (sb + 1)) / SBD);
    for (int k = tid; k < PART; k += 512) cnt[k] = 0;
    __syncthreads();
    for (int e = lo + tid; e < hi; e += 512)
        atomicAdd(&cnt[packed[e] >> SRCB], 1);
    __syncthreads();
    int* outp = degpart + (size_t)blockIdx.x * PART;
    for (int k = tid; k < PART; k += 512) outp[k] = cnt[k];
}

__global__ __launch_bounds__(512) void dinvg_kernel(
    const int* __restrict__ degpart, const float* __restrict__ x,
    float* __restrict__ dinv, float* __restrict__ g, int n) {
    int i = blockIdx.x * 512 + threadIdx.x;
    if (i >= n) return;
    int p = i >> LPBIT, ld = i & (PART - 1);
    int deg = 0;
    #pragma unroll
    for (int sb = 0; sb < SBD; sb++)
        deg += degpart[(size_t)(p * SBD + sb) * PART + ld];
    float d = rsqrtf((float)deg + 1.0f);  // +1 self-loop
    dinv[i] = d;
    float2 xv = ((const float2*)x)[i];
    ((float2*)g)[i] = make_float2(xv.x * d, xv.y * d);
}

// ---------------- LDS-atomic aggregation, layer 1 (2 comps) --------------
// SoA planes acc[c][2048]: ds_add banks = ld%32 (random, ~2-way, ~free).

__global__ __launch_bounds__(512) void agg1h_kernel(
    const unsigned* __restrict__ packed, const int* __restrict__ colStart,
    const float* __restrict__ g, float* __restrict__ part1) {
    __shared__ float acc[2][PART];
    int tid = threadIdx.x;
    int p = blockIdx.x / SB1, sb = blockIdx.x - p * SB1;
    int s0 = colStart[p], len = colStart[p + 1] - s0;
    int lo = s0 + (int)(((long long)len * sb) / SB1);
    int hi = s0 + (int)(((long long)len * (sb + 1)) / SB1);
    for (int k = tid; k < 2 * PART; k += 512) ((float*)acc)[k] = 0.0f;
    __syncthreads();
    const float2* gp = (const float2*)g;
    for (int e = lo + tid; e < hi; e += 512) {
        unsigned w = packed[e];
        int ld = (int)(w >> SRCB);
        int src = (int)(w & ((1u << SRCB) - 1));
        float2 gv = gp[src];
        atomicAdd(&acc[0][ld], gv.x);
        atomicAdd(&acc[1][ld], gv.y);
    }
    __syncthreads();
    float* outp = part1 + (size_t)blockIdx.x * (2 * PART);
    for (int k = tid; k < 2 * PART; k += 512) outp[k] = ((float*)acc)[k];
}

__global__ __launch_bounds__(512) void combine1_kernel(
    const float* __restrict__ part1, const float* __restrict__ g,
    const float* __restrict__ dinv, const float* __restrict__ W1,
    const float* __restrict__ b1, const float* __restrict__ W2,
    float* __restrict__ hs2, int n) {
    int i = blockIdx.x * 512 + threadIdx.x;
    if (i >= n) return;
    int p = i >> LPBIT, ld = i & (PART - 1);
    size_t base = (size_t)(p * SB1) * (2 * PART) + ld;
    float s0 = 0.0f, s1 = 0.0f;
    #pragma unroll
    for (int sb = 0; sb < SB1; sb++) {
        s0 += part1[base + (size_t)sb * (2 * PART)];
        s1 += part1[base + (size_t)sb * (2 * PART) + PART];
    }
    float d = dinv[i];
    float2 gi = ((const float2*)g)[i];
    s0 = (s0 + gi.x) * d;
    s1 = (s1 + gi.y) * d;
    float oc0 = 0.0f, oc1 = 0.0f, oc2 = 0.0f, oc3 = 0.0f;
    #pragma unroll
    for (int f = 0; f < 8; f++) {
        float h = fmaxf(s0 * W1[f] + s1 * W1[8 + f] + b1[f], 0.0f);
        oc0 += h * W2[4 * f];
        oc1 += h * W2[4 * f + 1];
        oc2 += h * W2[4 * f + 2];
        oc3 += h * W2[4 * f + 3];
    }
    float4 o;
    o.x = oc0 * d; o.y = oc1 * d; o.z = oc2 * d; o.w = oc3 * d;
    ((float4*)hs2)[i] = o;
}

// ---------------- LDS-atomic aggregation, layer 2 (4 comps) --------------

__global__ __launch_bounds__(512) void agg2h_kernel(
    const unsigned* __restrict__ packed, const int* __restrict__ colStart,
    const float* __restrict__ hs2, float* __restrict__ part2) {
    __shared__ float acc[4][PART];
    int tid = threadIdx.x;
    int p = blockIdx.x / SB2, sb = blockIdx.x - p * SB2;
    int s0 = colStart[p], len = colStart[p + 1] - s0;
    int lo = s0 + (int)(((long long)len * sb) / SB2);
    int hi = s0 + (int)(((long long)len * (sb + 1)) / SB2);
    for (int k = tid; k < 4 * PART; k += 512) ((float*)acc)[k] = 0.0f;
    __syncthreads();
    const float4* hp = (const float4*)hs2;
    for (int e = lo + tid; e < hi; e += 512) {
        unsigned w = packed[e];
        int ld = (int)(w >> SRCB);
        int src = (int)(w & ((1u << SRCB) - 1));
        float4 hv = hp[src];
        atomicAdd(&acc[0][ld], hv.x);
        atomicAdd(&acc[1][ld], hv.y);
        atomicAdd(&acc[2][ld], hv.z);
        atomicAdd(&acc[3][ld], hv.w);
    }
    __syncthreads();
    float* outp = part2 + (size_t)blockIdx.x * (4 * PART);
    for (int k = tid; k < 4 * PART; k += 512) outp[k] = ((float*)acc)[k];
}

__global__ __launch_bounds__(512) void combine2_kernel(
    const float* __restrict__ part2, const float* __restrict__ hs2,
    const float* __restrict__ dinv, const float* __restrict__ b2,
    float* __restrict__ out, int n) {
    int i = blockIdx.x * 512 + threadIdx.x;
    if (i >= n) return;
    int p = i >> LPBIT, ld = i & (PART - 1);
    size_t base = (size_t)(p * SB2) * (4 * PART) + ld;
    float s0 = 0.0f, s1 = 0.0f, s2 = 0.0f, s3 = 0.0f;
    #pragma unroll
    for (int sb = 0; sb < SB2; sb++) {
        const float* q = part2 + base + (size_t)sb * (4 * PART);
        s0 += q[0];
        s1 += q[PART];
        s2 += q[2 * PART];
        s3 += q[3 * PART];
    }
    float d = dinv[i];
    float4 hv = ((const float4*)hs2)[i];
    float4 o;
    o.x = d * (s0 + hv.x) + b2[0];
    o.y = d * (s1 + hv.y) + b2[1];
    o.z = d * (s2 + hv.z) + b2[2];
    o.w = d * (s3 + hv.w) + b2[3];
    ((float4*)out)[i] = o;
}

extern "C" void kernel_launch(void* const* d_in, const int* in_sizes, int n_in,
                              void* d_out, int out_size, void* d_ws, size_t ws_size,
                              hipStream_t stream) {
    const float* x   = (const float*)d_in[0];
    const int*   ei  = (const int*)d_in[1];
    const float* W1  = (const float*)d_in[2];
    const float* b1  = (const float*)d_in[3];
    const float* W2  = (const float*)d_in[4];
    const float* b2  = (const float*)d_in[5];
    float* out = (float*)d_out;

    const int n = in_sizes[0] / 2;  // x is [N,2]
    const int E = in_sizes[1] / 2;  // edge_index is [2,E]
    const int* src = ei;
    const int* dst = ei + E;

    const int P  = (n + PART - 1) >> LPBIT;  // 98
    const int B1 = (E + EPB - 1) / EPB;      // 782

    int* ws = (int*)d_ws;
    int* colTotal = ws;                                      // 1024
    int* colStart = ws + 1024;                               // 1024
    int* cntmatA  = ws + 2048;                               // B1*P
    size_t cmsz = (((size_t)B1 * P) + 3) & ~(size_t)3;
    unsigned* packed = (unsigned*)(cntmatA + cmsz);          // E
    size_t nd = (size_t)P << LPBIT;                          // 200704
    float* dinv = (float*)(packed + E);                      // nd
    float* g    = dinv + nd;                                 // 2*nd
    float* hs2  = g + 2 * nd;                                // 4*nd
    // time-overlaid partial region (deg -> part1 -> part2):
    float* partial = hs2 + 4 * nd;   // max(SBD*P*2048, SB1*P*4096, SB2*P*8192) words
    int*   degpart = (int*)partial;
    float* part1   = partial;
    float* part2   = partial;

    const int gN = (n + 511) / 512;

    countA_kernel    <<<B1, 512, 0, stream>>>(dst, cntmatA, E, P);
    colscanA_kernel  <<<P, 256, 0, stream>>>(cntmatA, colTotal, B1, P);
    totalscanA_kernel<<<1, 256, 0, stream>>>(colTotal, colStart, P, E);
    scatterA_kernel  <<<B1, 512, 0, stream>>>(src, dst, cntmatA, colStart, packed, E, P);
    deghist_kernel   <<<P * SBD, 512, 0, stream>>>(packed, colStart, degpart);
    dinvg_kernel     <<<gN, 512, 0, stream>>>(degpart, x, dinv, g, n);
    agg1h_kernel     <<<P * SB1, 512, 0, stream>>>(packed, colStart, g, part1);
    combine1_kernel  <<<gN, 512, 0, stream>>>(part1, g, dinv, W1, b1, W2, hs2, n);
    agg2h_kernel     <<<P * SB2, 512, 0, stream>>>(packed, colStart, hs2, part2);
    combine2_kernel  <<<gN, 512, 0, stream>>>(part2, hs2, dinv, b2, out, n);
}